// Round 8
// baseline (196.908 us; speedup 1.0000x reference)
//
#include <hip/hip_runtime.h>
#include <hip/hip_bf16.h>
#include <stdint.h>

#define N_   8
#define C_   256
#define H_   64
#define W_   64
#define CO_  256
#define K_   9
#define HO_  64
#define WO_  64
#define CK_  (C_ * K_)    // 2304
#define P_   (HO_ * WO_)  // 4096

#define BN   64           // p per block (fast path)
#define BK   64           // ck per K-step (2 MFMA K-slices)
#define NT   36           // K-steps: 9 taps x 4 channel-quarters
#define NTHR 512          // 8 waves

typedef __attribute__((ext_vector_type(8))) short bf16x8;
typedef __attribute__((ext_vector_type(4))) float f32x4;

__device__ __forceinline__ unsigned short f2bf(float f) {
    uint32_t u = __builtin_bit_cast(uint32_t, f);
    uint32_t r = (u + 0x7FFFu + ((u >> 16) & 1u)) >> 16;
    return (unsigned short)r;
}
__device__ __forceinline__ float bf2f(unsigned short u) {
    return __builtin_bit_cast(float, (uint32_t)u << 16);
}
__device__ __forceinline__ float h2f(unsigned short u) {
    return (float)__builtin_bit_cast(_Float16, u);
}
__device__ __forceinline__ unsigned short f2h(float f) {
    return __builtin_bit_cast(unsigned short, (_Float16)f);
}

// ================= FAST PATH (needs 17,956,864 B of d_ws) =================

// pre-pass A: x[n][c][hw] f32 -> xT[n][hw][c] bf16
__global__ __launch_bounds__(256)
void transpose_x(const float* __restrict__ x, unsigned short* __restrict__ xT) {
    __shared__ float t[64][65];
    const int n  = blockIdx.z;
    const int c0 = blockIdx.y * 64;
    const int h0 = blockIdx.x * 64;
    const int tx = threadIdx.x & 63;
    const int ty = threadIdx.x >> 6;   // 0..3
    const float* xp = x + ((size_t)n * C_ + c0) * P_ + h0;
    #pragma unroll
    for (int i = 0; i < 16; ++i) {
        int c = ty * 16 + i;
        t[c][tx] = xp[(size_t)c * P_ + tx];
    }
    __syncthreads();
    unsigned short* op = xT + ((size_t)n * P_ + h0) * C_ + c0;
    #pragma unroll
    for (int i = 0; i < 16; ++i) {
        int hw = ty * 16 + i;
        op[(size_t)hw * C_ + tx] = f2bf(t[tx][hw]);
    }
}

// pre-pass B: weight[co][c][k] f32 -> Wt[co][k][c] bf16
__global__ __launch_bounds__(256)
void reorder_w(const float* __restrict__ w, unsigned short* __restrict__ Wt) {
    const int co = blockIdx.x;
    const int c  = threadIdx.x;
    const float* src = w + (size_t)co * CK_ + (size_t)c * K_;
    float v[9];
    #pragma unroll
    for (int k = 0; k < 9; ++k) v[k] = src[k];
    #pragma unroll
    for (int k = 0; k < 9; ++k)
        Wt[(size_t)co * CK_ + k * C_ + c] = f2bf(v[k]);
}

// Main fused kernel: BK=64, T14 issue-early/write-late pipeline, 8-slot XOR swizzle,
// f16-packed bilinear weights (LDS 50176 B -> 3 blocks/CU), cvt_pk bf16 packing.
__global__ __launch_bounds__(NTHR, 6)
void dcn_main(const unsigned short* __restrict__ xT,
              const unsigned short* __restrict__ Wt,
              const float* __restrict__ offset,
              const float* __restrict__ mask,
              float* __restrict__ out) {
    __shared__ uint2  sIdx[BN * K_];              // 4608 B: 4x u16 corner idx
    __shared__ uint2  sW  [BN * K_];              // 4608 B: 4x f16 corner weights
    __shared__ unsigned short sWs[CO_ * BK];      // 32 KB
    __shared__ unsigned short sBs[BN * BK];       //  8 KB   -> total 50176 B

    const int tid = threadIdx.x;
    // XCD-pin: bid%8 = XCD = batch image; per-XCD working set ~3.6MB fits 4MB L2.
    const int bid = blockIdx.x;
    const int n   = bid & 7;
    const int p0  = (bid >> 3) * BN;

    for (int e = tid; e < BN * K_; e += NTHR) {
        int pl = e / K_;
        int k  = e - pl * K_;
        int p  = p0 + pl;
        int ho = p >> 6, wo = p & 63;
        float offy = offset[(size_t)((n * 2 * K_ + 2 * k)     * P_) + p];
        float offx = offset[(size_t)((n * 2 * K_ + 2 * k + 1) * P_) + p];
        float m    = mask  [(size_t)((n * K_ + k) * P_) + p];
        float py = (float)(k / 3 + ho - 1) + offy;
        float px = (float)(k % 3 + wo - 1) + offx;
        float y0f = floorf(py), x0f = floorf(px);
        float ly = py - y0f,   lx = px - x0f;
        int y0 = (int)y0f, x0 = (int)x0f;
        int y1 = y0 + 1,   x1 = x0 + 1;
        bool vy0 = (y0 >= 0) & (y0 < H_);
        bool vy1 = (y1 >= 0) & (y1 < H_);
        bool vx0 = (x0 >= 0) & (x0 < W_);
        bool vx1 = (x1 >= 0) & (x1 < W_);
        float w00 = (1.f - ly) * (1.f - lx) * m * ((vy0 & vx0) ? 1.f : 0.f);
        float w01 = (1.f - ly) * lx         * m * ((vy0 & vx1) ? 1.f : 0.f);
        float w10 = ly * (1.f - lx)         * m * ((vy1 & vx0) ? 1.f : 0.f);
        float w11 = ly * lx                 * m * ((vy1 & vx1) ? 1.f : 0.f);
        unsigned int cy0 = (unsigned)min(max(y0, 0), H_ - 1);
        unsigned int cy1 = (unsigned)min(max(y1, 0), H_ - 1);
        unsigned int cx0 = (unsigned)min(max(x0, 0), W_ - 1);
        unsigned int cx1 = (unsigned)min(max(x1, 0), W_ - 1);
        sIdx[e] = make_uint2((cy0 * W_ + cx0) | ((cy0 * W_ + cx1) << 16),
                             (cy1 * W_ + cx0) | ((cy1 * W_ + cx1) << 16));
        sW[e]   = make_uint2((unsigned)f2h(w00) | ((unsigned)f2h(w01) << 16),
                             (unsigned)f2h(w10) | ((unsigned)f2h(w11) << 16));
    }
    __syncthreads();   // params visible before prefetch(0) reads sIdx

    const unsigned short* xTn = xT + (size_t)n * P_ * C_;

    // ---- roles ----
    // sampling: (p-row, 8-channel sub-block)
    const int spl = tid >> 3;                 // 0..63
    const int cs8 = (tid & 7) * 8;            // 0..56
    char* bdst = (char*)sBs + spl * 128 + ((((tid & 7)) ^ (spl & 7)) << 4);
    // weight: (co row, 64B half-row)
    const int wco  = tid >> 1;                // 0..255
    const int wchq = (tid & 1) * 4;           // slot base 0 or 4
    const int wswz = wco & 7;
    char* wrow = (char*)sWs + wco * 128;
    const unsigned short* wsrcbase = Wt + (size_t)wco * CK_ + (tid & 1) * 32;

    const int lane = tid & 63;
    const int wid  = tid >> 6;
    const int wm   = (wid & 3) * 64;
    const int wp   = (wid >> 2) * 32;
    const int l15  = lane & 15;
    const int l4   = lane >> 4;               // 0..3
    const int slA  = l4 ^ (l15 & 7);          // ks=0 slot; ks=1 -> slA^4

    f32x4 acc[4][2] = {};

    // prefetch registers (tile t+1 in flight during tile t's MFMA)
    uint4 qa, qb, qc, qd;        // 4 bilinear corners x 8 channels
    uint4 wq0, wq1, wq2, wq3;    // 64B of weight row

    // ---- prefetch tile 0 ----
    {
        const int k = 0, c0 = 0;
        const unsigned short* ws = wsrcbase + k * C_ + c0;
        wq0 = *(const uint4*)(ws);
        wq1 = *(const uint4*)(ws + 8);
        wq2 = *(const uint4*)(ws + 16);
        wq3 = *(const uint4*)(ws + 24);
        uint2 id = sIdx[spl * K_ + k];
        const unsigned short* base = xTn + c0 + cs8;
        qa = *(const uint4*)(base + ((size_t)(id.x & 0xFFFFu) << 8));
        qb = *(const uint4*)(base + ((size_t)(id.x >> 16)     << 8));
        qc = *(const uint4*)(base + ((size_t)(id.y & 0xFFFFu) << 8));
        qd = *(const uint4*)(base + ((size_t)(id.y >> 16)     << 8));
    }

    for (int t = 0; t < NT; ++t) {
        const int k = t >> 2;

        __syncthreads();   // all MFMA reads of tile t-1 done

        // ---- write-late: combine + stage tile t from prefetched regs ----
        {
            *(uint4*)(wrow + (((wchq + 0) ^ wswz) << 4)) = wq0;
            *(uint4*)(wrow + (((wchq + 1) ^ wswz) << 4)) = wq1;
            *(uint4*)(wrow + (((wchq + 2) ^ wswz) << 4)) = wq2;
            *(uint4*)(wrow + (((wchq + 3) ^ wswz) << 4)) = wq3;

            uint2 wv = sW[spl * K_ + k];
            float w0 = h2f((unsigned short)(wv.x & 0xFFFF));
            float w1 = h2f((unsigned short)(wv.x >> 16));
            float w2 = h2f((unsigned short)(wv.y & 0xFFFF));
            float w3 = h2f((unsigned short)(wv.y >> 16));
            const unsigned* pa = (const unsigned*)&qa;
            const unsigned* pb = (const unsigned*)&qb;
            const unsigned* pc = (const unsigned*)&qc;
            const unsigned* pd = (const unsigned*)&qd;
            unsigned rr[4];
            #pragma unroll
            for (int h = 0; h < 4; ++h) {
                unsigned ua = pa[h], ub = pb[h], uc = pc[h], ud = pd[h];
                float v0 = w0 * bf2f((unsigned short)(ua & 0xFFFF))
                         + w1 * bf2f((unsigned short)(ub & 0xFFFF))
                         + w2 * bf2f((unsigned short)(uc & 0xFFFF))
                         + w3 * bf2f((unsigned short)(ud & 0xFFFF));
                float v1 = w0 * bf2f((unsigned short)(ua >> 16))
                         + w1 * bf2f((unsigned short)(ub >> 16))
                         + w2 * bf2f((unsigned short)(uc >> 16))
                         + w3 * bf2f((unsigned short)(ud >> 16));
                // pack 2x f32 -> 2x bf16 (RNE) in one instruction
                asm("v_cvt_pk_bf16_f32 %0, %1, %2" : "=v"(rr[h]) : "v"(v0), "v"(v1));
            }
            *(uint4*)bdst = make_uint4(rr[0], rr[1], rr[2], rr[3]);
        }

        // ---- issue-early: prefetch tile t+1 (lands under MFMA + next barrier) ----
        if (t + 1 < NT) {
            const int kn  = (t + 1) >> 2;
            const int c0n = ((t + 1) & 3) * 64;
            const unsigned short* ws = wsrcbase + kn * C_ + c0n;
            wq0 = *(const uint4*)(ws);
            wq1 = *(const uint4*)(ws + 8);
            wq2 = *(const uint4*)(ws + 16);
            wq3 = *(const uint4*)(ws + 24);
            uint2 id = sIdx[spl * K_ + kn];
            const unsigned short* base = xTn + c0n + cs8;
            qa = *(const uint4*)(base + ((size_t)(id.x & 0xFFFFu) << 8));
            qb = *(const uint4*)(base + ((size_t)(id.x >> 16)     << 8));
            qc = *(const uint4*)(base + ((size_t)(id.y & 0xFFFFu) << 8));
            qd = *(const uint4*)(base + ((size_t)(id.y >> 16)     << 8));
        }

        __syncthreads();   // tile t staged

        // ---- MFMA: 2 K-slices x 4 m x 2 n ----
        #pragma unroll
        for (int ks = 0; ks < 2; ++ks) {
            const int sl = slA ^ (ks << 2);
            bf16x8 b0 = *(const bf16x8*)((const char*)sBs + (wp      + l15) * 128 + (sl << 4));
            bf16x8 b1 = *(const bf16x8*)((const char*)sBs + (wp + 16 + l15) * 128 + (sl << 4));
            #pragma unroll
            for (int m = 0; m < 4; ++m) {
                bf16x8 a = *(const bf16x8*)((const char*)sWs + (wm + m * 16 + l15) * 128 + (sl << 4));
                acc[m][0] = __builtin_amdgcn_mfma_f32_16x16x32_bf16(a, b0, acc[m][0], 0, 0, 0);
                acc[m][1] = __builtin_amdgcn_mfma_f32_16x16x32_bf16(a, b1, acc[m][1], 0, 0, 0);
            }
        }
    }

    float* outn = out + (size_t)n * CO_ * P_;
    #pragma unroll
    for (int m = 0; m < 4; ++m) {
        int co = wm + m * 16 + l4 * 4;
        #pragma unroll
        for (int nn = 0; nn < 2; ++nn) {
            int p = p0 + wp + nn * 16 + l15;
            #pragma unroll
            for (int r = 0; r < 4; ++r) {
                outn[(size_t)(co + r) * P_ + p] = acc[m][nn][r];
            }
        }
    }
}

// ================= FALLBACK (round-2 kernel, zero scratch, proven pass) =================
template <int TAG>
__global__ __launch_bounds__(512, 2)
void dcn_fb(const float* __restrict__ x,
            const float* __restrict__ offset,
            const float* __restrict__ mask,
            const float* __restrict__ weight,
            float* __restrict__ out) {
    __shared__ uint2  sIdx[128 * K_];
    __shared__ float4 sW  [128 * K_];
    __shared__ unsigned short sWs[CO_ * 32];
    __shared__ unsigned short sBs[128 * 32];

    const int tid = threadIdx.x;
    const int n  = blockIdx.y;
    const int p0 = blockIdx.x * 128;

    for (int e = tid; e < 128 * K_; e += 512) {
        int pl = e / K_;
        int k  = e - pl * K_;
        int p  = p0 + pl;
        int ho = p >> 6, wo = p & 63;
        float offy = offset[(size_t)((n * 2 * K_ + 2 * k)     * P_) + p];
        float offx = offset[(size_t)((n * 2 * K_ + 2 * k + 1) * P_) + p];
        float m    = mask  [(size_t)((n * K_ + k) * P_) + p];
        float py = (float)(k / 3 + ho - 1) + offy;
        float px = (float)(k % 3 + wo - 1) + offx;
        float y0f = floorf(py), x0f = floorf(px);
        float ly = py - y0f,   lx = px - x0f;
        int y0 = (int)y0f, x0 = (int)x0f;
        int y1 = y0 + 1,   x1 = x0 + 1;
        bool vy0 = (y0 >= 0) & (y0 < H_);
        bool vy1 = (y1 >= 0) & (y1 < H_);
        bool vx0 = (x0 >= 0) & (x0 < W_);
        bool vx1 = (x1 >= 0) & (x1 < W_);
        float w00 = (1.f - ly) * (1.f - lx) * m * ((vy0 & vx0) ? 1.f : 0.f);
        float w01 = (1.f - ly) * lx         * m * ((vy0 & vx1) ? 1.f : 0.f);
        float w10 = ly * (1.f - lx)         * m * ((vy1 & vx0) ? 1.f : 0.f);
        float w11 = ly * lx                 * m * ((vy1 & vx1) ? 1.f : 0.f);
        unsigned int cy0 = (unsigned)min(max(y0, 0), H_ - 1);
        unsigned int cy1 = (unsigned)min(max(y1, 0), H_ - 1);
        unsigned int cx0 = (unsigned)min(max(x0, 0), W_ - 1);
        unsigned int cx1 = (unsigned)min(max(x1, 0), W_ - 1);
        sIdx[e] = make_uint2((cy0 * W_ + cx0) | ((cy0 * W_ + cx1) << 16),
                             (cy1 * W_ + cx0) | ((cy1 * W_ + cx1) << 16));
        sW[e]   = make_float4(w00, w01, w10, w11);
    }

    const float* xn = x + (size_t)n * C_ * P_;
    const int pl   = tid >> 2;
    const int pl9  = pl * K_;
    const int ckb  = (tid & 3) * 8;
    const int wco  = tid >> 1;
    const int wck  = (tid & 1) * 16;

    const int lane = tid & 63;
    const int wid  = tid >> 6;
    const int wm   = (wid & 1) * 128;
    const int wp   = (wid >> 1) * 32;
    const int l15  = lane & 15;
    const int l4   = lane >> 4;

    f32x4 acc[8][2] = {};

    for (int ck0 = 0; ck0 < CK_; ck0 += 32) {
        __syncthreads();
        {
            const float4* wsrc = (const float4*)(weight + (size_t)wco * CK_ + ck0 + wck);
            float4 wa = wsrc[0], wb = wsrc[1], wc = wsrc[2], wd = wsrc[3];
            uint4 q0, q1;
            q0.x = f2bf(wa.x) | ((unsigned)f2bf(wa.y) << 16);
            q0.y = f2bf(wa.z) | ((unsigned)f2bf(wa.w) << 16);
            q0.z = f2bf(wb.x) | ((unsigned)f2bf(wb.y) << 16);
            q0.w = f2bf(wb.z) | ((unsigned)f2bf(wb.w) << 16);
            q1.x = f2bf(wc.x) | ((unsigned)f2bf(wc.y) << 16);
            q1.y = f2bf(wc.z) | ((unsigned)f2bf(wc.w) << 16);
            q1.z = f2bf(wd.x) | ((unsigned)f2bf(wd.y) << 16);
            q1.w = f2bf(wd.z) | ((unsigned)f2bf(wd.w) << 16);
            *(uint4*)&sWs[wco * 32 + wck]     = q0;
            *(uint4*)&sWs[wco * 32 + wck + 8] = q1;
        }
        {
            int ckstart = ck0 + ckb;
            int cc = ckstart / 9;
            int kk = ckstart - cc * 9;
            unsigned int packed[4];
            unsigned short colv[8];
            #pragma unroll
            for (int j = 0; j < 8; ++j) {
                int e = pl9 + kk;
                uint2  id = sIdx[e];
                float4 wv = sW[e];
                const float* xp = xn + ((size_t)cc << 12);
                float v = wv.x * xp[id.x & 0xFFFFu]
                        + wv.y * xp[id.x >> 16]
                        + wv.z * xp[id.y & 0xFFFFu]
                        + wv.w * xp[id.y >> 16];
                colv[j] = f2bf(v);
                ++kk; if (kk == 9) { kk = 0; ++cc; }
            }
            packed[0] = colv[0] | ((unsigned)colv[1] << 16);
            packed[1] = colv[2] | ((unsigned)colv[3] << 16);
            packed[2] = colv[4] | ((unsigned)colv[5] << 16);
            packed[3] = colv[6] | ((unsigned)colv[7] << 16);
            *(uint4*)&sBs[pl * 32 + ckb] = *(uint4*)packed;
        }
        __syncthreads();
        bf16x8 bfr0 = *(const bf16x8*)&sBs[(wp + l15)      * 32 + l4 * 8];
        bf16x8 bfr1 = *(const bf16x8*)&sBs[(wp + 16 + l15) * 32 + l4 * 8];
        #pragma unroll
        for (int m = 0; m < 8; ++m) {
            bf16x8 afr = *(const bf16x8*)&sWs[(wm + m * 16 + l15) * 32 + l4 * 8];
            acc[m][0] = __builtin_amdgcn_mfma_f32_16x16x32_bf16(afr, bfr0, acc[m][0], 0, 0, 0);
            acc[m][1] = __builtin_amdgcn_mfma_f32_16x16x32_bf16(afr, bfr1, acc[m][1], 0, 0, 0);
        }
    }

    float* outn = out + (size_t)n * CO_ * P_;
    #pragma unroll
    for (int m = 0; m < 8; ++m) {
        int co = wm + m * 16 + l4 * 4;
        #pragma unroll
        for (int nn = 0; nn < 2; ++nn) {
            int p = p0 + wp + nn * 16 + l15;
            #pragma unroll
            for (int r = 0; r < 4; ++r) {
                outn[(size_t)(co + r) * P_ + p] = acc[m][nn][r];
            }
        }
    }
}

extern "C" void kernel_launch(void* const* d_in, const int* in_sizes, int n_in,
                              void* d_out, int out_size, void* d_ws, size_t ws_size,
                              hipStream_t stream) {
    const float* x      = (const float*)d_in[0];
    const float* offset = (const float*)d_in[1];
    const float* mask   = (const float*)d_in[2];
    const float* weight = (const float*)d_in[3];
    float* out = (float*)d_out;

    const size_t xT_elems = (size_t)N_ * P_ * C_;            // 8,388,608 ushort
    const size_t Wt_elems = (size_t)CO_ * CK_;               //   589,824 ushort
    const size_t need     = (xT_elems + Wt_elems) * sizeof(unsigned short); // 17,956,864 B

    if (ws_size >= need) {
        unsigned short* xT = (unsigned short*)d_ws;
        unsigned short* Wt = xT + xT_elems;
        transpose_x<<<dim3(P_ / 64, C_ / 64, N_), dim3(256), 0, stream>>>(x, xT);
        reorder_w<<<dim3(CO_), dim3(256), 0, stream>>>(weight, Wt);
        dcn_main<<<dim3((P_ / BN) * N_), dim3(NTHR), 0, stream>>>(xT, Wt, offset, mask, out);
    } else if (ws_size >= (8u << 20)) {
        dcn_fb<1><<<dim3(P_ / 128, N_), dim3(512), 0, stream>>>(x, offset, mask, weight, out);
    } else {
        dcn_fb<0><<<dim3(P_ / 128, N_), dim3(512), 0, stream>>>(x, offset, mask, weight, out);
    }
}

// Round 9
// 83.589 us; speedup vs baseline: 2.3557x; 2.3557x over previous
//
#include <hip/hip_runtime.h>
#include <hip/hip_bf16.h>
#include <stdint.h>

#define N_   8
#define C_   256
#define H_   64
#define W_   64
#define CO_  256
#define K_   9
#define HO_  64
#define WO_  64
#define CK_  (C_ * K_)    // 2304
#define P_   (HO_ * WO_)  // 4096

#define BN   64           // p per block (fast path)
#define BK   64           // ck per K-step (2 MFMA K-slices)
#define NT   36           // K-steps: 9 taps x 4 channel-quarters
#define NTHR 512          // 8 waves

typedef __attribute__((ext_vector_type(8))) short bf16x8;
typedef __attribute__((ext_vector_type(4))) float f32x4;

__device__ __forceinline__ unsigned short f2bf(float f) {
    uint32_t u = __builtin_bit_cast(uint32_t, f);
    uint32_t r = (u + 0x7FFFu + ((u >> 16) & 1u)) >> 16;
    return (unsigned short)r;
}
__device__ __forceinline__ float bf2f(unsigned short u) {
    return __builtin_bit_cast(float, (uint32_t)u << 16);
}
__device__ __forceinline__ float h2f(unsigned short u) {
    return (float)__builtin_bit_cast(_Float16, u);
}
__device__ __forceinline__ unsigned short f2h(float f) {
    return __builtin_bit_cast(unsigned short, (_Float16)f);
}

// ================= FAST PATH (needs 17,956,864 B of d_ws) =================

// pre-pass A: x[n][c][hw] f32 -> xT[n][hw][c] bf16
__global__ __launch_bounds__(256)
void transpose_x(const float* __restrict__ x, unsigned short* __restrict__ xT) {
    __shared__ float t[64][65];
    const int n  = blockIdx.z;
    const int c0 = blockIdx.y * 64;
    const int h0 = blockIdx.x * 64;
    const int tx = threadIdx.x & 63;
    const int ty = threadIdx.x >> 6;   // 0..3
    const float* xp = x + ((size_t)n * C_ + c0) * P_ + h0;
    #pragma unroll
    for (int i = 0; i < 16; ++i) {
        int c = ty * 16 + i;
        t[c][tx] = xp[(size_t)c * P_ + tx];
    }
    __syncthreads();
    unsigned short* op = xT + ((size_t)n * P_ + h0) * C_ + c0;
    #pragma unroll
    for (int i = 0; i < 16; ++i) {
        int hw = ty * 16 + i;
        op[(size_t)hw * C_ + tx] = f2bf(t[tx][hw]);
    }
}

// pre-pass B: weight[co][c][k] f32 -> Wt[co][k][c] bf16
__global__ __launch_bounds__(256)
void reorder_w(const float* __restrict__ w, unsigned short* __restrict__ Wt) {
    const int co = blockIdx.x;
    const int c  = threadIdx.x;
    const float* src = w + (size_t)co * CK_ + (size_t)c * K_;
    float v[9];
    #pragma unroll
    for (int k = 0; k < 9; ++k) v[k] = src[k];
    #pragma unroll
    for (int k = 0; k < 9; ++k)
        Wt[(size_t)co * CK_ + k * C_ + c] = f2bf(v[k]);
}

// Raw-barrier helpers: __syncthreads() forces s_waitcnt vmcnt(0) before s_barrier,
// which drains our in-flight prefetch loads. These keep vmem loads alive across
// the barrier (only LDS ops must be complete).
__device__ __forceinline__ void barrier_lgkm_only() {
    __builtin_amdgcn_sched_barrier(0);
    asm volatile("s_waitcnt lgkmcnt(0)" ::: "memory");
    __builtin_amdgcn_s_barrier();
    __builtin_amdgcn_sched_barrier(0);
}

// Main fused kernel: BK=64, T14 issue-early/write-late + raw barriers (loads
// survive both barriers; vmcnt drained only at the consume point one full
// iteration after issue). 8-slot XOR swizzle, f16 bilinear weights.
// launch_bounds(512,4): VGPR cap 128 — rnd8's (512,6) cap 85 caused scratch
// spill (WRITE_SIZE 33->270 MB); acc(32 AGPR)+prefetch(32)+addr needs ~92.
__global__ __launch_bounds__(NTHR, 4)
void dcn_main(const unsigned short* __restrict__ xT,
              const unsigned short* __restrict__ Wt,
              const float* __restrict__ offset,
              const float* __restrict__ mask,
              float* __restrict__ out) {
    __shared__ uint2  sIdx[BN * K_];              // 4608 B: 4x u16 corner idx (write-once)
    __shared__ uint2  sW  [BN * K_];              // 4608 B: 4x f16 corner weights (write-once)
    __shared__ unsigned short sWs[CO_ * BK];      // 32 KB (rewritten per iter)
    __shared__ unsigned short sBs[BN * BK];       //  8 KB (rewritten per iter)  -> 50176 B

    const int tid = threadIdx.x;
    // XCD-pin: bid%8 = XCD = batch image; per-XCD working set ~3.6MB fits 4MB L2.
    const int bid = blockIdx.x;
    const int n   = bid & 7;
    const int p0  = (bid >> 3) * BN;

    for (int e = tid; e < BN * K_; e += NTHR) {
        int pl = e / K_;
        int k  = e - pl * K_;
        int p  = p0 + pl;
        int ho = p >> 6, wo = p & 63;
        float offy = offset[(size_t)((n * 2 * K_ + 2 * k)     * P_) + p];
        float offx = offset[(size_t)((n * 2 * K_ + 2 * k + 1) * P_) + p];
        float m    = mask  [(size_t)((n * K_ + k) * P_) + p];
        float py = (float)(k / 3 + ho - 1) + offy;
        float px = (float)(k % 3 + wo - 1) + offx;
        float y0f = floorf(py), x0f = floorf(px);
        float ly = py - y0f,   lx = px - x0f;
        int y0 = (int)y0f, x0 = (int)x0f;
        int y1 = y0 + 1,   x1 = x0 + 1;
        bool vy0 = (y0 >= 0) & (y0 < H_);
        bool vy1 = (y1 >= 0) & (y1 < H_);
        bool vx0 = (x0 >= 0) & (x0 < W_);
        bool vx1 = (x1 >= 0) & (x1 < W_);
        float w00 = (1.f - ly) * (1.f - lx) * m * ((vy0 & vx0) ? 1.f : 0.f);
        float w01 = (1.f - ly) * lx         * m * ((vy0 & vx1) ? 1.f : 0.f);
        float w10 = ly * (1.f - lx)         * m * ((vy1 & vx0) ? 1.f : 0.f);
        float w11 = ly * lx                 * m * ((vy1 & vx1) ? 1.f : 0.f);
        unsigned int cy0 = (unsigned)min(max(y0, 0), H_ - 1);
        unsigned int cy1 = (unsigned)min(max(y1, 0), H_ - 1);
        unsigned int cx0 = (unsigned)min(max(x0, 0), W_ - 1);
        unsigned int cx1 = (unsigned)min(max(x1, 0), W_ - 1);
        sIdx[e] = make_uint2((cy0 * W_ + cx0) | ((cy0 * W_ + cx1) << 16),
                             (cy1 * W_ + cx0) | ((cy1 * W_ + cx1) << 16));
        sW[e]   = make_uint2((unsigned)f2h(w00) | ((unsigned)f2h(w01) << 16),
                             (unsigned)f2h(w10) | ((unsigned)f2h(w11) << 16));
    }
    __syncthreads();   // params visible before prefetch(0) reads sIdx (full drain ok, once)

    const unsigned short* xTn = xT + (size_t)n * P_ * C_;

    // ---- roles ----
    const int spl = tid >> 3;                 // 0..63
    const int cs8 = (tid & 7) * 8;            // 0..56
    char* bdst = (char*)sBs + spl * 128 + ((((tid & 7)) ^ (spl & 7)) << 4);
    const int wco  = tid >> 1;                // 0..255
    const int wchq = (tid & 1) * 4;           // slot base 0 or 4
    const int wswz = wco & 7;
    char* wrow = (char*)sWs + wco * 128;
    const unsigned short* wsrcbase = Wt + (size_t)wco * CK_ + (tid & 1) * 32;

    const int lane = tid & 63;
    const int wid  = tid >> 6;
    const int wm   = (wid & 3) * 64;
    const int wp   = (wid >> 2) * 32;
    const int l15  = lane & 15;
    const int l4   = lane >> 4;               // 0..3
    const int slA  = l4 ^ (l15 & 7);          // ks=0 slot; ks=1 -> slA^4

    f32x4 acc[4][2] = {};

    // prefetch registers (tile t+1 in flight during tile t's MFMA + both barriers)
    uint4 qa, qb, qc, qd;        // 4 bilinear corners x 8 channels
    uint4 wq0, wq1, wq2, wq3;    // 64B of weight row

    // ---- prefetch tile 0 ----
    {
        const unsigned short* ws = wsrcbase;
        wq0 = *(const uint4*)(ws);
        wq1 = *(const uint4*)(ws + 8);
        wq2 = *(const uint4*)(ws + 16);
        wq3 = *(const uint4*)(ws + 24);
        uint2 id = sIdx[spl * K_];
        const unsigned short* base = xTn + cs8;
        qa = *(const uint4*)(base + ((size_t)(id.x & 0xFFFFu) << 8));
        qb = *(const uint4*)(base + ((size_t)(id.x >> 16)     << 8));
        qc = *(const uint4*)(base + ((size_t)(id.y & 0xFFFFu) << 8));
        qd = *(const uint4*)(base + ((size_t)(id.y >> 16)     << 8));
    }

    for (int t = 0; t < NT; ++t) {
        const int k = t >> 2;

        // B1: all waves' ds_reads (MFMA operands of t-1) complete before overwrite.
        // lgkm-only: the 8 global loads issued last iter stay in flight.
        barrier_lgkm_only();

        // consume point: prefetched loads for tile t must have landed
        asm volatile("s_waitcnt vmcnt(0)" ::: "memory");

        // ---- write-late: combine + stage tile t from prefetched regs ----
        {
            *(uint4*)(wrow + (((wchq + 0) ^ wswz) << 4)) = wq0;
            *(uint4*)(wrow + (((wchq + 1) ^ wswz) << 4)) = wq1;
            *(uint4*)(wrow + (((wchq + 2) ^ wswz) << 4)) = wq2;
            *(uint4*)(wrow + (((wchq + 3) ^ wswz) << 4)) = wq3;

            uint2 wv = sW[spl * K_ + k];
            float w0 = h2f((unsigned short)(wv.x & 0xFFFF));
            float w1 = h2f((unsigned short)(wv.x >> 16));
            float w2 = h2f((unsigned short)(wv.y & 0xFFFF));
            float w3 = h2f((unsigned short)(wv.y >> 16));
            const unsigned* pa = (const unsigned*)&qa;
            const unsigned* pb = (const unsigned*)&qb;
            const unsigned* pc = (const unsigned*)&qc;
            const unsigned* pd = (const unsigned*)&qd;
            unsigned rr[4];
            #pragma unroll
            for (int h = 0; h < 4; ++h) {
                unsigned ua = pa[h], ub = pb[h], uc = pc[h], ud = pd[h];
                float v0 = w0 * bf2f((unsigned short)(ua & 0xFFFF))
                         + w1 * bf2f((unsigned short)(ub & 0xFFFF))
                         + w2 * bf2f((unsigned short)(uc & 0xFFFF))
                         + w3 * bf2f((unsigned short)(ud & 0xFFFF));
                float v1 = w0 * bf2f((unsigned short)(ua >> 16))
                         + w1 * bf2f((unsigned short)(ub >> 16))
                         + w2 * bf2f((unsigned short)(uc >> 16))
                         + w3 * bf2f((unsigned short)(ud >> 16));
                asm("v_cvt_pk_bf16_f32 %0, %1, %2" : "=v"(rr[h]) : "v"(v0), "v"(v1));
            }
            *(uint4*)bdst = make_uint4(rr[0], rr[1], rr[2], rr[3]);
        }

        // ---- issue-early: prefetch tile t+1 (survives both barriers) ----
        if (t + 1 < NT) {
            const int kn  = (t + 1) >> 2;
            const int c0n = ((t + 1) & 3) * 64;
            const unsigned short* ws = wsrcbase + kn * C_ + c0n;
            wq0 = *(const uint4*)(ws);
            wq1 = *(const uint4*)(ws + 8);
            wq2 = *(const uint4*)(ws + 16);
            wq3 = *(const uint4*)(ws + 24);
            uint2 id = sIdx[spl * K_ + kn];
            const unsigned short* base = xTn + c0n + cs8;
            qa = *(const uint4*)(base + ((size_t)(id.x & 0xFFFFu) << 8));
            qb = *(const uint4*)(base + ((size_t)(id.x >> 16)     << 8));
            qc = *(const uint4*)(base + ((size_t)(id.y & 0xFFFFu) << 8));
            qd = *(const uint4*)(base + ((size_t)(id.y >> 16)     << 8));
        }

        // B2: tile t staged (ds_writes visible); do NOT drain vmcnt here.
        barrier_lgkm_only();

        // ---- MFMA: 2 K-slices x 4 m x 2 n ----
        #pragma unroll
        for (int ks = 0; ks < 2; ++ks) {
            const int sl = slA ^ (ks << 2);
            bf16x8 b0 = *(const bf16x8*)((const char*)sBs + (wp      + l15) * 128 + (sl << 4));
            bf16x8 b1 = *(const bf16x8*)((const char*)sBs + (wp + 16 + l15) * 128 + (sl << 4));
            #pragma unroll
            for (int m = 0; m < 4; ++m) {
                bf16x8 a = *(const bf16x8*)((const char*)sWs + (wm + m * 16 + l15) * 128 + (sl << 4));
                acc[m][0] = __builtin_amdgcn_mfma_f32_16x16x32_bf16(a, b0, acc[m][0], 0, 0, 0);
                acc[m][1] = __builtin_amdgcn_mfma_f32_16x16x32_bf16(a, b1, acc[m][1], 0, 0, 0);
            }
        }
    }

    float* outn = out + (size_t)n * CO_ * P_;
    #pragma unroll
    for (int m = 0; m < 4; ++m) {
        int co = wm + m * 16 + l4 * 4;
        #pragma unroll
        for (int nn = 0; nn < 2; ++nn) {
            int p = p0 + wp + nn * 16 + l15;
            #pragma unroll
            for (int r = 0; r < 4; ++r) {
                outn[(size_t)(co + r) * P_ + p] = acc[m][nn][r];
            }
        }
    }
}

// ================= FALLBACK (round-2 kernel, zero scratch, proven pass) =================
template <int TAG>
__global__ __launch_bounds__(512, 2)
void dcn_fb(const float* __restrict__ x,
            const float* __restrict__ offset,
            const float* __restrict__ mask,
            const float* __restrict__ weight,
            float* __restrict__ out) {
    __shared__ uint2  sIdx[128 * K_];
    __shared__ float4 sW  [128 * K_];
    __shared__ unsigned short sWs[CO_ * 32];
    __shared__ unsigned short sBs[128 * 32];

    const int tid = threadIdx.x;
    const int n  = blockIdx.y;
    const int p0 = blockIdx.x * 128;

    for (int e = tid; e < 128 * K_; e += 512) {
        int pl = e / K_;
        int k  = e - pl * K_;
        int p  = p0 + pl;
        int ho = p >> 6, wo = p & 63;
        float offy = offset[(size_t)((n * 2 * K_ + 2 * k)     * P_) + p];
        float offx = offset[(size_t)((n * 2 * K_ + 2 * k + 1) * P_) + p];
        float m    = mask  [(size_t)((n * K_ + k) * P_) + p];
        float py = (float)(k / 3 + ho - 1) + offy;
        float px = (float)(k % 3 + wo - 1) + offx;
        float y0f = floorf(py), x0f = floorf(px);
        float ly = py - y0f,   lx = px - x0f;
        int y0 = (int)y0f, x0 = (int)x0f;
        int y1 = y0 + 1,   x1 = x0 + 1;
        bool vy0 = (y0 >= 0) & (y0 < H_);
        bool vy1 = (y1 >= 0) & (y1 < H_);
        bool vx0 = (x0 >= 0) & (x0 < W_);
        bool vx1 = (x1 >= 0) & (x1 < W_);
        float w00 = (1.f - ly) * (1.f - lx) * m * ((vy0 & vx0) ? 1.f : 0.f);
        float w01 = (1.f - ly) * lx         * m * ((vy0 & vx1) ? 1.f : 0.f);
        float w10 = ly * (1.f - lx)         * m * ((vy1 & vx0) ? 1.f : 0.f);
        float w11 = ly * lx                 * m * ((vy1 & vx1) ? 1.f : 0.f);
        unsigned int cy0 = (unsigned)min(max(y0, 0), H_ - 1);
        unsigned int cy1 = (unsigned)min(max(y1, 0), H_ - 1);
        unsigned int cx0 = (unsigned)min(max(x0, 0), W_ - 1);
        unsigned int cx1 = (unsigned)min(max(x1, 0), W_ - 1);
        sIdx[e] = make_uint2((cy0 * W_ + cx0) | ((cy0 * W_ + cx1) << 16),
                             (cy1 * W_ + cx0) | ((cy1 * W_ + cx1) << 16));
        sW[e]   = make_float4(w00, w01, w10, w11);
    }

    const float* xn = x + (size_t)n * C_ * P_;
    const int pl   = tid >> 2;
    const int pl9  = pl * K_;
    const int ckb  = (tid & 3) * 8;
    const int wco  = tid >> 1;
    const int wck  = (tid & 1) * 16;

    const int lane = tid & 63;
    const int wid  = tid >> 6;
    const int wm   = (wid & 1) * 128;
    const int wp   = (wid >> 1) * 32;
    const int l15  = lane & 15;
    const int l4   = lane >> 4;

    f32x4 acc[8][2] = {};

    for (int ck0 = 0; ck0 < CK_; ck0 += 32) {
        __syncthreads();
        {
            const float4* wsrc = (const float4*)(weight + (size_t)wco * CK_ + ck0 + wck);
            float4 wa = wsrc[0], wb = wsrc[1], wc = wsrc[2], wd = wsrc[3];
            uint4 q0, q1;
            q0.x = f2bf(wa.x) | ((unsigned)f2bf(wa.y) << 16);
            q0.y = f2bf(wa.z) | ((unsigned)f2bf(wa.w) << 16);
            q0.z = f2bf(wb.x) | ((unsigned)f2bf(wb.y) << 16);
            q0.w = f2bf(wb.z) | ((unsigned)f2bf(wb.w) << 16);
            q1.x = f2bf(wc.x) | ((unsigned)f2bf(wc.y) << 16);
            q1.y = f2bf(wc.z) | ((unsigned)f2bf(wc.w) << 16);
            q1.z = f2bf(wd.x) | ((unsigned)f2bf(wd.y) << 16);
            q1.w = f2bf(wd.z) | ((unsigned)f2bf(wd.w) << 16);
            *(uint4*)&sWs[wco * 32 + wck]     = q0;
            *(uint4*)&sWs[wco * 32 + wck + 8] = q1;
        }
        {
            int ckstart = ck0 + ckb;
            int cc = ckstart / 9;
            int kk = ckstart - cc * 9;
            unsigned int packed[4];
            unsigned short colv[8];
            #pragma unroll
            for (int j = 0; j < 8; ++j) {
                int e = pl9 + kk;
                uint2  id = sIdx[e];
                float4 wv = sW[e];
                const float* xp = xn + ((size_t)cc << 12);
                float v = wv.x * xp[id.x & 0xFFFFu]
                        + wv.y * xp[id.x >> 16]
                        + wv.z * xp[id.y & 0xFFFFu]
                        + wv.w * xp[id.y >> 16];
                colv[j] = f2bf(v);
                ++kk; if (kk == 9) { kk = 0; ++cc; }
            }
            packed[0] = colv[0] | ((unsigned)colv[1] << 16);
            packed[1] = colv[2] | ((unsigned)colv[3] << 16);
            packed[2] = colv[4] | ((unsigned)colv[5] << 16);
            packed[3] = colv[6] | ((unsigned)colv[7] << 16);
            *(uint4*)&sBs[pl * 32 + ckb] = *(uint4*)packed;
        }
        __syncthreads();
        bf16x8 bfr0 = *(const bf16x8*)&sBs[(wp + l15)      * 32 + l4 * 8];
        bf16x8 bfr1 = *(const bf16x8*)&sBs[(wp + 16 + l15) * 32 + l4 * 8];
        #pragma unroll
        for (int m = 0; m < 8; ++m) {
            bf16x8 afr = *(const bf16x8*)&sWs[(wm + m * 16 + l15) * 32 + l4 * 8];
            acc[m][0] = __builtin_amdgcn_mfma_f32_16x16x32_bf16(afr, bfr0, acc[m][0], 0, 0, 0);
            acc[m][1] = __builtin_amdgcn_mfma_f32_16x16x32_bf16(afr, bfr1, acc[m][1], 0, 0, 0);
        }
    }

    float* outn = out + (size_t)n * CO_ * P_;
    #pragma unroll
    for (int m = 0; m < 8; ++m) {
        int co = wm + m * 16 + l4 * 4;
        #pragma unroll
        for (int nn = 0; nn < 2; ++nn) {
            int p = p0 + wp + nn * 16 + l15;
            #pragma unroll
            for (int r = 0; r < 4; ++r) {
                outn[(size_t)(co + r) * P_ + p] = acc[m][nn][r];
            }
        }
    }
}

extern "C" void kernel_launch(void* const* d_in, const int* in_sizes, int n_in,
                              void* d_out, int out_size, void* d_ws, size_t ws_size,
                              hipStream_t stream) {
    const float* x      = (const float*)d_in[0];
    const float* offset = (const float*)d_in[1];
    const float* mask   = (const float*)d_in[2];
    const float* weight = (const float*)d_in[3];
    float* out = (float*)d_out;

    const size_t xT_elems = (size_t)N_ * P_ * C_;            // 8,388,608 ushort
    const size_t Wt_elems = (size_t)CO_ * CK_;               //   589,824 ushort
    const size_t need     = (xT_elems + Wt_elems) * sizeof(unsigned short); // 17,956,864 B

    if (ws_size >= need) {
        unsigned short* xT = (unsigned short*)d_ws;
        unsigned short* Wt = xT + xT_elems;
        transpose_x<<<dim3(P_ / 64, C_ / 64, N_), dim3(256), 0, stream>>>(x, xT);
        reorder_w<<<dim3(CO_), dim3(256), 0, stream>>>(weight, Wt);
        dcn_main<<<dim3((P_ / BN) * N_), dim3(NTHR), 0, stream>>>(xT, Wt, offset, mask, out);
    } else if (ws_size >= (8u << 20)) {
        dcn_fb<1><<<dim3(P_ / 128, N_), dim3(512), 0, stream>>>(x, offset, mask, weight, out);
    } else {
        dcn_fb<0><<<dim3(P_ / 128, N_), dim3(512), 0, stream>>>(x, offset, mask, weight, out);
    }
}